// Round 12
// baseline (279.853 us; speedup 1.0000x reference)
//
#include <hip/hip_runtime.h>
#include <stdint.h>

#define B_ 4
#define S_ 1024
#define D_ 2048
#define H_ 16
#define HD 128
#define E_ 6144

typedef short bf16x8 __attribute__((ext_vector_type(8)));
typedef float f32x4 __attribute__((ext_vector_type(4)));

__device__ __forceinline__ unsigned short f2bf(float f) {
  union { float f; unsigned u; } x; x.f = f;
  unsigned r = x.u + 0x7fffu + ((x.u >> 16) & 1u);
  return (unsigned short)(r >> 16);
}

__device__ __forceinline__ void gl_lds16(const void* g, void* l) {
  __builtin_amdgcn_global_load_lds(
      (const __attribute__((address_space(1))) void*)g,
      (__attribute__((address_space(3))) void*)l, 16, 0, 0);
}

// DPP cross-lane within the 16-lane row: single-cycle VALU, no LDS pipe.
template <int C>
__device__ __forceinline__ float dppf(float x) {
  union { float f; int i; } u; u.f = x;
  u.i = __builtin_amdgcn_update_dpp(u.i, u.i, C, 0xF, 0xF, true);
  return u.f;
}
__device__ __forceinline__ float red_max16(float v) {
  v = fmaxf(v, dppf<0xB1>(v));   // quad_perm [1,0,3,2]  (xor 1)
  v = fmaxf(v, dppf<0x4E>(v));   // quad_perm [2,3,0,1]  (xor 2)
  v = fmaxf(v, dppf<0x124>(v));  // row_ror:4
  v = fmaxf(v, dppf<0x128>(v));  // row_ror:8
  return v;
}
__device__ __forceinline__ float red_sum16(float v) {
  v += dppf<0xB1>(v);
  v += dppf<0x4E>(v);
  v += dppf<0x124>(v);
  v += dppf<0x128>(v);
  return v;
}

// ---- fused preprocessing: X cvt (2048 blk) | W cvt (3072 blk) | rope (256 blk)
__global__ __launch_bounds__(256) void prep(const float* __restrict__ X,
                                            short* __restrict__ Xt,
                                            const float* __restrict__ W,
                                            short* __restrict__ Wt,
                                            float2* __restrict__ tbl) {
  int blk = blockIdx.x;
  const int tid = threadIdx.x;

  if (blk >= 5120) {  // rope table: [s][j], j in [0,64)
    int idx = (blk - 5120) * 256 + tid;  // 65536
    int s = idx >> 6, j = idx & 63;
    float inv = exp2f(-0.20762050593045953f * (float)j);
    float a = (float)s * inv;
    tbl[idx] = make_float2(cosf(a), sinf(a));
    return;
  }

  const float* src;
  short* dst;
  if (blk < 2048) {
    src = X; dst = Xt;
  } else {
    blk -= 2048; src = W; dst = Wt;
  }

  __shared__ __align__(16) short L[128 * 40];
  const int kt = blk & 63, mt = blk >> 6;
  {
    int row = tid >> 1, half = tid & 1;
    const float* p = src + (size_t)(mt * 128 + row) * D_ + kt * 32 + half * 16;
    float4 v0 = *(const float4*)(p);
    float4 v1 = *(const float4*)(p + 4);
    float4 v2 = *(const float4*)(p + 8);
    float4 v3 = *(const float4*)(p + 12);
    union { short s[16]; int4 v[2]; } u;
    u.s[0] = (short)f2bf(v0.x);  u.s[1] = (short)f2bf(v0.y);
    u.s[2] = (short)f2bf(v0.z);  u.s[3] = (short)f2bf(v0.w);
    u.s[4] = (short)f2bf(v1.x);  u.s[5] = (short)f2bf(v1.y);
    u.s[6] = (short)f2bf(v1.z);  u.s[7] = (short)f2bf(v1.w);
    u.s[8] = (short)f2bf(v2.x);  u.s[9] = (short)f2bf(v2.y);
    u.s[10] = (short)f2bf(v2.z); u.s[11] = (short)f2bf(v2.w);
    u.s[12] = (short)f2bf(v3.x); u.s[13] = (short)f2bf(v3.y);
    u.s[14] = (short)f2bf(v3.z); u.s[15] = (short)f2bf(v3.w);
    int4* lp = (int4*)(L + row * 40 + half * 16);
    lp[0] = u.v[0];
    lp[1] = u.v[1];
  }
  __syncthreads();
  short* out = dst + (((size_t)(mt * 64 + kt)) << 12);
#pragma unroll
  for (int i = 0; i < 2; i++) {
    int ch = i * 256 + tid;
    int cc = ch & 15, qq = (ch >> 4) & 3, rt = ch >> 6;
    int4 v = *(const int4*)(L + (rt * 16 + cc) * 40 + qq * 8);
    *(int4*)(out + ch * 8) = v;
  }
}

// ---------------- QKV GEMM + bias + RoPE + fragment-order scatter ----------
// R3 structure (reproduced 3x: 106-108 us, MfmaUtil 43%): 4 waves (2M x 2N),
// per-wave 128x64 (acc[8][4]), block tile 256x128, BK=32, grid 48x16 = 768
// blocks, LDS 72KB tri-buffer -> 2 blocks/CU (desynchronized blocks fill
// each other's barrier stalls; 1-entity/CU variants = 29-31%).
// Depth-2 prefetch, counted vmcnt(6) never drained mid-loop, 1 barrier/step.
// PLATEAU DECLARED: 4 structural attempts to exceed 43% failed (R1 phase-
// split, R4 1-block 8-wave, R5 B-global+drain, R8 B-asm-reg spill).
__global__ __launch_bounds__(256, 2) void qkv_gemm(
    const short* __restrict__ Xt, const short* __restrict__ Wt,
    const float* __restrict__ bq, const float2* __restrict__ rope,
    short* __restrict__ Qg, short* __restrict__ Kg, short* __restrict__ Vg) {
  __shared__ __align__(16) short As[3][2][4096];  // [slot][row-half]  48 KB
  __shared__ __align__(16) short Bs[3][4096];     // [slot]            24 KB

  const int tid = threadIdx.x;
  const int w = tid >> 6, lane = tid & 63;
  const int q = lane >> 4, c = lane & 15;
  const int wm = w >> 1, wn = w & 1;
  const int bn = blockIdx.x, bm = blockIdx.y;

  const short* Ab = Xt + (size_t)(bm * 2) * 64 * 4096;  // 2 row-halves x 64 chunks
  const short* Bb = Wt + (size_t)bn * 64 * 4096;

  // stage one 4096-short chunk (8 KB) = 2 async 16B/lane loads per thread
#define STG(gsrc, ldst)                                              \
  do {                                                               \
    gl_lds16((gsrc) + tid * 8, (ldst) + tid * 8);                    \
    gl_lds16((gsrc) + 2048 + tid * 8, (ldst) + 2048 + tid * 8);      \
  } while (0)
#define STAGE_STEP(sl, mm)                                           \
  do {                                                               \
    STG(Ab + (size_t)(mm)*4096, &As[sl][0][0]);                      \
    STG(Ab + (size_t)(64 + (mm)) * 4096, &As[sl][1][0]);             \
    STG(Bb + (size_t)(mm)*4096, &Bs[sl][0]);                         \
  } while (0)

  int ctl[4];
#pragma unroll
  for (int jl = 0; jl < 4; jl++) ctl[jl] = 2 * wn + (jl & 1) + ((jl >> 1) << 2);

  f32x4 acc[8][4];
#pragma unroll
  for (int i = 0; i < 8; i++)
#pragma unroll
    for (int jl = 0; jl < 4; jl++) acc[i][jl] = (f32x4){0.f, 0.f, 0.f, 0.f};

  // prologue: chunks of steps 0 (slot 0) and 1 (slot 1); 12 loads in flight
  STAGE_STEP(0, 0);
  STAGE_STEP(1, 1);
  asm volatile("s_waitcnt vmcnt(6)" ::: "memory");  // step-0 chunks landed
  __builtin_amdgcn_s_barrier();

  int s = 0;
  for (int m = 0; m < 64; m++) {
    bf16x8 a[8], b[4];
#pragma unroll
    for (int i = 0; i < 8; i++)
      a[i] = *(const bf16x8*)(&As[s][wm][i * 512 + lane * 8]);
#pragma unroll
    for (int jl = 0; jl < 4; jl++)
      b[jl] = *(const bf16x8*)(&Bs[s][ctl[jl] * 512 + lane * 8]);

    if (m + 2 < 64) {
      int s2 = s + 2;
      if (s2 >= 3) s2 -= 3;
      STAGE_STEP(s2, m + 2);
    }

    __builtin_amdgcn_s_setprio(1);
#pragma unroll
    for (int i = 0; i < 8; i++)
#pragma unroll
      for (int jl = 0; jl < 4; jl++)
        acc[i][jl] = __builtin_amdgcn_mfma_f32_16x16x32_bf16(a[i], b[jl],
                                                             acc[i][jl], 0, 0, 0);
    __builtin_amdgcn_s_setprio(0);

    if (m < 62) asm volatile("s_waitcnt vmcnt(6)" ::: "memory");
    else        asm volatile("s_waitcnt vmcnt(0)" ::: "memory");
    __builtin_amdgcn_s_barrier();  // slot (m+1)%3 published to all waves

    s = (s == 2) ? 0 : s + 1;
  }
#undef STG
#undef STAGE_STEP

  // ---------------- epilogue: bias + RoPE + fragment-order scatter ----------
  const int head = bn / 3, typ = bn - head * 3;
  const int b_ = bm >> 2;
  const int bh = b_ * H_ + head;
  const int sb = ((bm & 3) << 8) + wm * 128;  // wave's first seq row (128 rows)
  const int slab0 = sb >> 6;                  // first of two 64-row k/v slabs

  float bias[4];
#pragma unroll
  for (int jl = 0; jl < 4; jl++) bias[jl] = bq[bn * 128 + ctl[jl] * 16 + c];
#pragma unroll
  for (int i = 0; i < 8; i++)
#pragma unroll
    for (int jl = 0; jl < 4; jl++)
#pragma unroll
      for (int r = 0; r < 4; r++) acc[i][jl][r] += bias[jl];

  if (typ < 2) {
#pragma unroll
    for (int i = 0; i < 8; i++)
#pragma unroll
      for (int r = 0; r < 4; r++) {
        int sg = sb + i * 16 + q * 4 + r;
#pragma unroll
        for (int jl = 0; jl < 2; jl++) {
          float2 cs = rope[sg * 64 + ctl[jl] * 16 + c];
          float x1 = acc[i][jl][r], x2 = acc[i][jl + 2][r];
          acc[i][jl][r] = x1 * cs.x - x2 * cs.y;
          acc[i][jl + 2][r] = x2 * cs.x + x1 * cs.y;
        }
      }
    if (typ == 0) {
      short* dst = Qg + (size_t)bh * S_ * HD;
#pragma unroll
      for (int i = 0; i < 8; i++)
#pragma unroll
        for (int r = 0; r < 4; r++) {
          int sg = sb + i * 16 + q * 4 + r;
          short* row = dst + (size_t)sg * HD;
#pragma unroll
          for (int jl = 0; jl < 4; jl++)
            row[ctl[jl] * 16 + c] = (short)f2bf(acc[i][jl][r] * 0.08838834764831845f);
        }
    } else {
      short* dstK = Kg + (size_t)bh * 16 * 8192 + (size_t)slab0 * 8192;
#pragma unroll
      for (int i = 0; i < 8; i++) {
        short* dsl = dstK + (i >> 2) * 8192;
        int ii = i & 3;
#pragma unroll
        for (int jl = 0; jl < 4; jl++) {
          int ks = ctl[jl] >> 1;
          int qqf = ((ctl[jl] & 1) << 1) + (c >> 3);
          short* p = dsl + (ks * 4 + ii) * 512 + qqf * 128 + (c & 7);
#pragma unroll
          for (int r = 0; r < 4; r++)
            p[(q * 4 + r) * 8] = (short)f2bf(acc[i][jl][r]);
        }
      }
    }
  } else {
    short* dstV = Vg + (size_t)bh * 16 * 8192 + (size_t)slab0 * 8192;
#pragma unroll
    for (int i = 0; i < 8; i++) {
      short* dsl = dstV + (i >> 2) * 8192;
      int iw = i & 3;
#pragma unroll
      for (int jl = 0; jl < 4; jl++)
#pragma unroll
        for (int r = 0; r < 4; r++) {
          int sl = q * 4 + r;
          int qqf = ((iw & 1) << 1) + (sl >> 3);
          dsl[((iw >> 1) * 8 + ctl[jl]) * 512 + qqf * 128 + c * 8 + (sl & 7)] =
              (short)f2bf(acc[i][jl][r]);
        }
    }
  }
}

// ---------------- causal flash attention ----------------
// R6 sync skeleton (proven: split counted waits, 2 barriers/iter, 4-wave
// blocks, 2 blocks/CU, grid (64,8), paired q-tiles -> 17 iters uniform).
// This round, three sync-preserving micro-cuts:
//  (1) P-store + ap preload hoisted BEFORE the V-wait/B2: Ps is wave-private
//      so no cross-wave ordering is needed; the ds latency hides under B2.
//  (2) exact-skip rescale: if no 16-lane group saw a new max, alpha == 1
//      bit-exactly -> skip 32 o-mults + exp + m/l-update (common after the
//      first few tiles of a causal row).
//  (3) s_setprio(1) around QK and PV MFMA clusters (T5).
__global__ __launch_bounds__(256, 2) void flash_attn(
    const short* __restrict__ Qg, const short* __restrict__ Kg,
    const short* __restrict__ Vg, float* __restrict__ out) {
  __shared__ __align__(16) short Kb[2][8192];  // 32 KB
  __shared__ __align__(16) short Vb[2][8192];  // 32 KB
  __shared__ __align__(16) short Ps[4096];     // 8 KB, wave-private 2 KB regions

  const int tid = threadIdx.x;
  const int w = tid >> 6, lane = tid & 63;
  const int q = lane >> 4, c = lane & 15;
  const int bh = blockIdx.x, pp = blockIdx.y;
  const int b = bh >> 4, h = bh & 15;

  const short* Qh = Qg + (size_t)bh * S_ * HD;
  const short* Kh = Kg + (size_t)bh * 16 * 8192;
  const short* Vh = Vg + (size_t)bh * 16 * 8192;

#pragma unroll
  for (int ph = 0; ph < 2; ph++) {
    const int qt = ph ? 15 - pp : pp;
    const int q0 = qt * 64;
    const int n = qt + 1;  // 64-wide k-tiles covering k < q0+64

    bf16x8 aq[4];  // wave w owns q-rows q0 + w*16 + [0,16)
#pragma unroll
    for (int ks = 0; ks < 4; ks++)
      aq[ks] = *(const bf16x8*)(Qh + (size_t)(q0 + w * 16 + c) * HD + ks * 32 + q * 8);

    f32x4 o[8];
    float m_[4], l_[4];
#pragma unroll
    for (int tjd = 0; tjd < 8; tjd++) o[tjd] = (f32x4){0.f, 0.f, 0.f, 0.f};
#pragma unroll
    for (int r = 0; r < 4; r++) { m_[r] = -1e30f; l_[r] = 0.f; }

    // prologue: stage K0 (4 instr/thread) then V0 (4 instr/thread)
#pragma unroll
    for (int i = 0; i < 4; i++) {
      int ch = i * 256 + tid;
      gl_lds16(Kh + ch * 8, &Kb[0][ch * 8]);
    }
#pragma unroll
    for (int i = 0; i < 4; i++) {
      int ch = i * 256 + tid;
      gl_lds16(Vh + ch * 8, &Vb[0][ch * 8]);
    }

    for (int it = 0; it < n; it++) {
      const int cur = it & 1;
      // retire K(it); V(it)'s 4 loads stay in flight
      asm volatile("s_waitcnt vmcnt(4)" ::: "memory");
      __builtin_amdgcn_s_barrier();  // B1: K(it) visible; all PV(it-1) done

      // prefetch K(it+1), V(it+1) into cur^1 buffers (safe: last readers of
      // cur^1 finished before B1 -- QK(it-1) pre-B2(it-1), PV(it-1) pre-B1)
      if (it + 1 < n) {
#pragma unroll
        for (int i = 0; i < 4; i++) {
          int ch = i * 256 + tid;
          gl_lds16(Kh + (size_t)(it + 1) * 8192 + ch * 8, &Kb[cur ^ 1][ch * 8]);
        }
#pragma unroll
        for (int i = 0; i < 4; i++) {
          int ch = i * 256 + tid;
          gl_lds16(Vh + (size_t)(it + 1) * 8192 + ch * 8, &Vb[cur ^ 1][ch * 8]);
        }
      }

      f32x4 s[4];
#pragma unroll
      for (int tj = 0; tj < 4; tj++) s[tj] = (f32x4){0.f, 0.f, 0.f, 0.f};
      __builtin_amdgcn_s_setprio(1);
#pragma unroll
      for (int ks = 0; ks < 4; ks++)
#pragma unroll
        for (int tj = 0; tj < 4; tj++) {
          bf16x8 bk = *(const bf16x8*)(&Kb[cur][(ks * 4 + tj) * 512 + lane * 8]);
          s[tj] = __builtin_amdgcn_mfma_f32_16x16x32_bf16(aq[ks], bk, s[tj], 0, 0, 0);
        }
      __builtin_amdgcn_s_setprio(0);

      if (it == qt) {  // diagonal tile: causal mask
#pragma unroll
        for (int tj = 0; tj < 4; tj++) {
          int kg = it * 64 + tj * 16 + c;
#pragma unroll
          for (int r = 0; r < 4; r++) {
            int qg = q0 + w * 16 + q * 4 + r;
            if (kg > qg) s[tj][r] = -1e30f;
          }
        }
      }

      // online softmax (DPP reductions within the 16-lane col group).
      // Exact-skip: if no group's max grew, every alpha == 1 bit-exactly.
#pragma unroll
      for (int r = 0; r < 4; r++) {
        float mx = fmaxf(fmaxf(s[0][r], s[1][r]), fmaxf(s[2][r], s[3][r]));
        mx = red_max16(mx);
        float mn = fmaxf(m_[r], mx);
        float rs = 0.f;
#pragma unroll
        for (int tj = 0; tj < 4; tj++) {
          float e = __expf(s[tj][r] - mn);
          s[tj][r] = e;
          rs += e;
        }
        rs = red_sum16(rs);
        if (__any(mx > m_[r])) {
          float alpha = __expf(m_[r] - mn);
          m_[r] = mn;
          l_[r] = l_[r] * alpha + rs;
#pragma unroll
          for (int tjd = 0; tjd < 8; tjd++) o[tjd][r] *= alpha;
        } else {
          l_[r] += rs;
        }
      }

      // P: C-layout -> wave-private A-layout region, BEFORE the V-wait: Ps
      // is wave-private (only this wave reads its 2KB region), so the
      // ds_write + ds_read latency hides under the vmcnt/B2 sync below.
#pragma unroll
      for (int tj = 0; tj < 4; tj++) {
        int base = w * 1024 + (tj >> 1) * 512 + (((tj & 1) << 1) + (c >> 3)) * 128 + (c & 7);
#pragma unroll
        for (int r = 0; r < 4; r++)
          Ps[base + (q * 4 + r) * 8] = (short)f2bf(s[tj][r]);
      }
      bf16x8 ap0 = *(const bf16x8*)(Ps + w * 1024 + lane * 8);
      bf16x8 ap1 = *(const bf16x8*)(Ps + w * 1024 + 512 + lane * 8);

      // retire V(it): K(it+1)+V(it+1) (8 newer loads) may remain in flight
      if (it + 1 < n)
        asm volatile("s_waitcnt vmcnt(8)" ::: "memory");
      else
        asm volatile("s_waitcnt vmcnt(0)" ::: "memory");
      __builtin_amdgcn_s_barrier();  // B2: V(it) visible

      __builtin_amdgcn_s_setprio(1);
#pragma unroll
      for (int tjd = 0; tjd < 8; tjd++) {
        bf16x8 bv = *(const bf16x8*)(&Vb[cur][tjd * 512 + lane * 8]);
        o[tjd] = __builtin_amdgcn_mfma_f32_16x16x32_bf16(ap0, bv, o[tjd], 0, 0, 0);
      }
#pragma unroll
      for (int tjd = 0; tjd < 8; tjd++) {
        bf16x8 bv = *(const bf16x8*)(&Vb[cur][(8 + tjd) * 512 + lane * 8]);
        o[tjd] = __builtin_amdgcn_mfma_f32_16x16x32_bf16(ap1, bv, o[tjd], 0, 0, 0);
      }
      __builtin_amdgcn_s_setprio(0);
    }

#pragma unroll
    for (int r = 0; r < 4; r++) {
      float inv = 1.0f / l_[r];
      int sg = q0 + w * 16 + q * 4 + r;
      float* dst = out + (size_t)(b * S_ + sg) * D_ + h * HD;
#pragma unroll
      for (int tjd = 0; tjd < 8; tjd++) dst[tjd * 16 + c] = o[tjd][r] * inv;
    }
    // phase boundary: all waves' PV reads of Kb/Vb[0..1] must complete before
    // next phase's prologue overwrites Kb[0]/Vb[0].
    __builtin_amdgcn_s_barrier();
  }
}

extern "C" void kernel_launch(void* const* d_in, const int* in_sizes, int n_in,
                              void* d_out, int out_size, void* d_ws, size_t ws_size,
                              hipStream_t stream) {
  (void)in_sizes; (void)n_in; (void)out_size; (void)ws_size;
  const float* hs = (const float*)d_in[0];
  const float* wq = (const float*)d_in[1];
  const float* bq = (const float*)d_in[2];
  char* ws = (char*)d_ws;
  short* Xt = (short*)(ws);
  short* Wt = (short*)(ws + 16777216);
  short* Qg = (short*)(ws + 41943040);
  short* Kg = (short*)(ws + 58720256);
  short* Vg = (short*)(ws + 75497472);
  float2* tbl = (float2*)(ws + 92274688);

  hipLaunchKernelGGL(prep, dim3(5376), dim3(256), 0, stream, hs, Xt, wq, Wt, tbl);
  hipLaunchKernelGGL(qkv_gemm, dim3(48, 16), dim3(256), 0, stream, Xt, Wt, bq, tbl, Qg, Kg, Vg);
  hipLaunchKernelGGL(flash_attn, dim3(64, 8), dim3(256), 0, stream, Qg, Kg, Vg, (float*)d_out);
}

// Round 13
// 271.438 us; speedup vs baseline: 1.0310x; 1.0310x over previous
//
#include <hip/hip_runtime.h>
#include <stdint.h>

#define B_ 4
#define S_ 1024
#define D_ 2048
#define H_ 16
#define HD 128
#define E_ 6144

typedef short bf16x8 __attribute__((ext_vector_type(8)));
typedef float f32x4 __attribute__((ext_vector_type(4)));

__device__ __forceinline__ unsigned short f2bf(float f) {
  union { float f; unsigned u; } x; x.f = f;
  unsigned r = x.u + 0x7fffu + ((x.u >> 16) & 1u);
  return (unsigned short)(r >> 16);
}

__device__ __forceinline__ void gl_lds16(const void* g, void* l) {
  __builtin_amdgcn_global_load_lds(
      (const __attribute__((address_space(1))) void*)g,
      (__attribute__((address_space(3))) void*)l, 16, 0, 0);
}

// DPP cross-lane within the 16-lane row: single-cycle VALU, no LDS pipe.
template <int C>
__device__ __forceinline__ float dppf(float x) {
  union { float f; int i; } u; u.f = x;
  u.i = __builtin_amdgcn_update_dpp(u.i, u.i, C, 0xF, 0xF, true);
  return u.f;
}
__device__ __forceinline__ float red_max16(float v) {
  v = fmaxf(v, dppf<0xB1>(v));   // quad_perm [1,0,3,2]  (xor 1)
  v = fmaxf(v, dppf<0x4E>(v));   // quad_perm [2,3,0,1]  (xor 2)
  v = fmaxf(v, dppf<0x124>(v));  // row_ror:4
  v = fmaxf(v, dppf<0x128>(v));  // row_ror:8
  return v;
}
__device__ __forceinline__ float red_sum16(float v) {
  v += dppf<0xB1>(v);
  v += dppf<0x4E>(v);
  v += dppf<0x124>(v);
  v += dppf<0x128>(v);
  return v;
}

// ---- fused preprocessing: X cvt (2048 blk) | W cvt (3072 blk) | rope (256 blk)
__global__ __launch_bounds__(256) void prep(const float* __restrict__ X,
                                            short* __restrict__ Xt,
                                            const float* __restrict__ W,
                                            short* __restrict__ Wt,
                                            float2* __restrict__ tbl) {
  int blk = blockIdx.x;
  const int tid = threadIdx.x;

  if (blk >= 5120) {  // rope table: [s][j], j in [0,64)
    int idx = (blk - 5120) * 256 + tid;  // 65536
    int s = idx >> 6, j = idx & 63;
    float inv = exp2f(-0.20762050593045953f * (float)j);
    float a = (float)s * inv;
    tbl[idx] = make_float2(cosf(a), sinf(a));
    return;
  }

  const float* src;
  short* dst;
  if (blk < 2048) {
    src = X; dst = Xt;
  } else {
    blk -= 2048; src = W; dst = Wt;
  }

  __shared__ __align__(16) short L[128 * 40];
  const int kt = blk & 63, mt = blk >> 6;
  {
    int row = tid >> 1, half = tid & 1;
    const float* p = src + (size_t)(mt * 128 + row) * D_ + kt * 32 + half * 16;
    float4 v0 = *(const float4*)(p);
    float4 v1 = *(const float4*)(p + 4);
    float4 v2 = *(const float4*)(p + 8);
    float4 v3 = *(const float4*)(p + 12);
    union { short s[16]; int4 v[2]; } u;
    u.s[0] = (short)f2bf(v0.x);  u.s[1] = (short)f2bf(v0.y);
    u.s[2] = (short)f2bf(v0.z);  u.s[3] = (short)f2bf(v0.w);
    u.s[4] = (short)f2bf(v1.x);  u.s[5] = (short)f2bf(v1.y);
    u.s[6] = (short)f2bf(v1.z);  u.s[7] = (short)f2bf(v1.w);
    u.s[8] = (short)f2bf(v2.x);  u.s[9] = (short)f2bf(v2.y);
    u.s[10] = (short)f2bf(v2.z); u.s[11] = (short)f2bf(v2.w);
    u.s[12] = (short)f2bf(v3.x); u.s[13] = (short)f2bf(v3.y);
    u.s[14] = (short)f2bf(v3.z); u.s[15] = (short)f2bf(v3.w);
    int4* lp = (int4*)(L + row * 40 + half * 16);
    lp[0] = u.v[0];
    lp[1] = u.v[1];
  }
  __syncthreads();
  short* out = dst + (((size_t)(mt * 64 + kt)) << 12);
#pragma unroll
  for (int i = 0; i < 2; i++) {
    int ch = i * 256 + tid;
    int cc = ch & 15, qq = (ch >> 4) & 3, rt = ch >> 6;
    int4 v = *(const int4*)(L + (rt * 16 + cc) * 40 + qq * 8);
    *(int4*)(out + ch * 8) = v;
  }
}

// ---------------- QKV GEMM + bias + RoPE + fragment-order scatter ----------
// R3 structure (reproduced 4x: 106-108 us, MfmaUtil 43%): 4 waves (2M x 2N),
// per-wave 128x64 (acc[8][4]), block tile 256x128, BK=32, grid 48x16 = 768
// blocks, LDS 72KB tri-buffer -> 2 blocks/CU (desynchronized blocks fill
// each other's barrier stalls; 1-entity/CU variants = 29-31%).
// Depth-2 prefetch, counted vmcnt(6) never drained mid-loop, 1 barrier/step.
// PLATEAU DECLARED: structural attempts to exceed 43% failed (R1, R4, R5, R8).
__global__ __launch_bounds__(256, 2) void qkv_gemm(
    const short* __restrict__ Xt, const short* __restrict__ Wt,
    const float* __restrict__ bq, const float2* __restrict__ rope,
    short* __restrict__ Qg, short* __restrict__ Kg, short* __restrict__ Vg) {
  __shared__ __align__(16) short As[3][2][4096];  // [slot][row-half]  48 KB
  __shared__ __align__(16) short Bs[3][4096];     // [slot]            24 KB

  const int tid = threadIdx.x;
  const int w = tid >> 6, lane = tid & 63;
  const int q = lane >> 4, c = lane & 15;
  const int wm = w >> 1, wn = w & 1;
  const int bn = blockIdx.x, bm = blockIdx.y;

  const short* Ab = Xt + (size_t)(bm * 2) * 64 * 4096;  // 2 row-halves x 64 chunks
  const short* Bb = Wt + (size_t)bn * 64 * 4096;

  // stage one 4096-short chunk (8 KB) = 2 async 16B/lane loads per thread
#define STG(gsrc, ldst)                                              \
  do {                                                               \
    gl_lds16((gsrc) + tid * 8, (ldst) + tid * 8);                    \
    gl_lds16((gsrc) + 2048 + tid * 8, (ldst) + 2048 + tid * 8);      \
  } while (0)
#define STAGE_STEP(sl, mm)                                           \
  do {                                                               \
    STG(Ab + (size_t)(mm)*4096, &As[sl][0][0]);                      \
    STG(Ab + (size_t)(64 + (mm)) * 4096, &As[sl][1][0]);             \
    STG(Bb + (size_t)(mm)*4096, &Bs[sl][0]);                         \
  } while (0)

  int ctl[4];
#pragma unroll
  for (int jl = 0; jl < 4; jl++) ctl[jl] = 2 * wn + (jl & 1) + ((jl >> 1) << 2);

  f32x4 acc[8][4];
#pragma unroll
  for (int i = 0; i < 8; i++)
#pragma unroll
    for (int jl = 0; jl < 4; jl++) acc[i][jl] = (f32x4){0.f, 0.f, 0.f, 0.f};

  // prologue: chunks of steps 0 (slot 0) and 1 (slot 1); 12 loads in flight
  STAGE_STEP(0, 0);
  STAGE_STEP(1, 1);
  asm volatile("s_waitcnt vmcnt(6)" ::: "memory");  // step-0 chunks landed
  __builtin_amdgcn_s_barrier();

  int s = 0;
  for (int m = 0; m < 64; m++) {
    bf16x8 a[8], b[4];
#pragma unroll
    for (int i = 0; i < 8; i++)
      a[i] = *(const bf16x8*)(&As[s][wm][i * 512 + lane * 8]);
#pragma unroll
    for (int jl = 0; jl < 4; jl++)
      b[jl] = *(const bf16x8*)(&Bs[s][ctl[jl] * 512 + lane * 8]);

    if (m + 2 < 64) {
      int s2 = s + 2;
      if (s2 >= 3) s2 -= 3;
      STAGE_STEP(s2, m + 2);
    }

    __builtin_amdgcn_s_setprio(1);
#pragma unroll
    for (int i = 0; i < 8; i++)
#pragma unroll
      for (int jl = 0; jl < 4; jl++)
        acc[i][jl] = __builtin_amdgcn_mfma_f32_16x16x32_bf16(a[i], b[jl],
                                                             acc[i][jl], 0, 0, 0);
    __builtin_amdgcn_s_setprio(0);

    if (m < 62) asm volatile("s_waitcnt vmcnt(6)" ::: "memory");
    else        asm volatile("s_waitcnt vmcnt(0)" ::: "memory");
    __builtin_amdgcn_s_barrier();  // slot (m+1)%3 published to all waves

    s = (s == 2) ? 0 : s + 1;
  }
#undef STG
#undef STAGE_STEP

  // ---------------- epilogue: bias + RoPE + fragment-order scatter ----------
  const int head = bn / 3, typ = bn - head * 3;
  const int b_ = bm >> 2;
  const int bh = b_ * H_ + head;
  const int sb = ((bm & 3) << 8) + wm * 128;  // wave's first seq row (128 rows)
  const int slab0 = sb >> 6;                  // first of two 64-row k/v slabs

  float bias[4];
#pragma unroll
  for (int jl = 0; jl < 4; jl++) bias[jl] = bq[bn * 128 + ctl[jl] * 16 + c];
#pragma unroll
  for (int i = 0; i < 8; i++)
#pragma unroll
    for (int jl = 0; jl < 4; jl++)
#pragma unroll
      for (int r = 0; r < 4; r++) acc[i][jl][r] += bias[jl];

  if (typ < 2) {
#pragma unroll
    for (int i = 0; i < 8; i++)
#pragma unroll
      for (int r = 0; r < 4; r++) {
        int sg = sb + i * 16 + q * 4 + r;
#pragma unroll
        for (int jl = 0; jl < 2; jl++) {
          float2 cs = rope[sg * 64 + ctl[jl] * 16 + c];
          float x1 = acc[i][jl][r], x2 = acc[i][jl + 2][r];
          acc[i][jl][r] = x1 * cs.x - x2 * cs.y;
          acc[i][jl + 2][r] = x2 * cs.x + x1 * cs.y;
        }
      }
    if (typ == 0) {
      short* dst = Qg + (size_t)bh * S_ * HD;
#pragma unroll
      for (int i = 0; i < 8; i++)
#pragma unroll
        for (int r = 0; r < 4; r++) {
          int sg = sb + i * 16 + q * 4 + r;
          short* row = dst + (size_t)sg * HD;
#pragma unroll
          for (int jl = 0; jl < 4; jl++)
            row[ctl[jl] * 16 + c] = (short)f2bf(acc[i][jl][r] * 0.08838834764831845f);
        }
    } else {
      short* dstK = Kg + (size_t)bh * 16 * 8192 + (size_t)slab0 * 8192;
#pragma unroll
      for (int i = 0; i < 8; i++) {
        short* dsl = dstK + (i >> 2) * 8192;
        int ii = i & 3;
#pragma unroll
        for (int jl = 0; jl < 4; jl++) {
          int ks = ctl[jl] >> 1;
          int qqf = ((ctl[jl] & 1) << 1) + (c >> 3);
          short* p = dsl + (ks * 4 + ii) * 512 + qqf * 128 + (c & 7);
#pragma unroll
          for (int r = 0; r < 4; r++)
            p[(q * 4 + r) * 8] = (short)f2bf(acc[i][jl][r]);
        }
      }
    }
  } else {
    short* dstV = Vg + (size_t)bh * 16 * 8192 + (size_t)slab0 * 8192;
#pragma unroll
    for (int i = 0; i < 8; i++) {
      short* dsl = dstV + (i >> 2) * 8192;
      int iw = i & 3;
#pragma unroll
      for (int jl = 0; jl < 4; jl++)
#pragma unroll
        for (int r = 0; r < 4; r++) {
          int sl = q * 4 + r;
          int qqf = ((iw & 1) << 1) + (sl >> 3);
          dsl[((iw >> 1) * 8 + ctl[jl]) * 512 + qqf * 128 + c * 8 + (sl & 7)] =
              (short)f2bf(acc[i][jl][r]);
        }
    }
  }
}

// ---------------- causal flash attention ----------------
// MERGED-TILE version of the proven R6 skeleton (R12's micro-cuts reverted:
// setprio/exact-skip/hoist regressed ~16 us as a bundle).
// Block (bh, j) owns q-tiles qa=perm[j] (in 0..7) and qb=15-qa (in 8..15) and
// runs ONE K-loop over k-tiles 0..qb serving both: tile A participates while
// it <= qa (diagonal mask at it == qa), tile B always (diagonal at it == qb).
// Per bh: 100 tile-iterations vs 136 in the 2-phase scheme (-26% barriers,
// -26% K/V staging bytes); MFMA work identical; per-tile op order identical
// -> bit-identical output. perm = {0,1,2,3,7,6,5,4}: co-resident pairs
// (id, id+256) sum to 25 k-iters each -> balanced CUs.
// Sync skeleton UNCHANGED from R6: vmcnt(4)/B1 | prefetch | QK | softmax |
// vmcnt(8)/B2 | P->PV. LDS 80 KB (Kb 32 + Vb 32 + PsA 8 + PsB 8) -> 2
// blocks/CU. 256 threads / 4 waves; wave w owns rows q0+w*16+[0,16).
__global__ __launch_bounds__(256, 2) void flash_attn(
    const short* __restrict__ Qg, const short* __restrict__ Kg,
    const short* __restrict__ Vg, float* __restrict__ out) {
  __shared__ __align__(16) short Kb[2][8192];  // 32 KB
  __shared__ __align__(16) short Vb[2][8192];  // 32 KB
  __shared__ __align__(16) short PsA[4096];    // 8 KB, wave-private 2 KB regions
  __shared__ __align__(16) short PsB[4096];    // 8 KB

  const int tid = threadIdx.x;
  const int w = tid >> 6, lane = tid & 63;
  const int q = lane >> 4, c = lane & 15;
  const int bh = blockIdx.x, j = blockIdx.y;
  const int b = bh >> 4, h = bh & 15;

  static const int perm[8] = {0, 1, 2, 3, 7, 6, 5, 4};
  const int qa = perm[j], qb = 15 - qa;
  const int q0A = qa * 64, q0B = qb * 64;
  const int n = qb + 1;  // loop over k-tiles 0..qb

  const short* Qh = Qg + (size_t)bh * S_ * HD;
  const short* Kh = Kg + (size_t)bh * 16 * 8192;
  const short* Vh = Vg + (size_t)bh * 16 * 8192;

  bf16x8 aqA[4], aqB[4];
#pragma unroll
  for (int ks = 0; ks < 4; ks++) {
    aqA[ks] = *(const bf16x8*)(Qh + (size_t)(q0A + w * 16 + c) * HD + ks * 32 + q * 8);
    aqB[ks] = *(const bf16x8*)(Qh + (size_t)(q0B + w * 16 + c) * HD + ks * 32 + q * 8);
  }

  f32x4 oA[8], oB[8];
  float mA[4], lA[4], mB[4], lB[4];
#pragma unroll
  for (int t = 0; t < 8; t++) {
    oA[t] = (f32x4){0.f, 0.f, 0.f, 0.f};
    oB[t] = (f32x4){0.f, 0.f, 0.f, 0.f};
  }
#pragma unroll
  for (int r = 0; r < 4; r++) {
    mA[r] = -1e30f; lA[r] = 0.f;
    mB[r] = -1e30f; lB[r] = 0.f;
  }

  // prologue: stage K0 (4 instr/thread) then V0 (4 instr/thread)
#pragma unroll
  for (int i = 0; i < 4; i++) {
    int ch = i * 256 + tid;
    gl_lds16(Kh + ch * 8, &Kb[0][ch * 8]);
  }
#pragma unroll
  for (int i = 0; i < 4; i++) {
    int ch = i * 256 + tid;
    gl_lds16(Vh + ch * 8, &Vb[0][ch * 8]);
  }

  for (int it = 0; it < n; it++) {
    const int cur = it & 1;
    const bool actA = (it <= qa);
    // retire K(it); V(it)'s 4 loads stay in flight
    asm volatile("s_waitcnt vmcnt(4)" ::: "memory");
    __builtin_amdgcn_s_barrier();  // B1: K(it) visible; all PV(it-1) done

    // prefetch K(it+1), V(it+1) into cur^1 buffers (safe: last readers of
    // cur^1 finished before B1 -- QK(it-1) pre-B2(it-1), PV(it-1) pre-B1)
    if (it + 1 < n) {
#pragma unroll
      for (int i = 0; i < 4; i++) {
        int ch = i * 256 + tid;
        gl_lds16(Kh + (size_t)(it + 1) * 8192 + ch * 8, &Kb[cur ^ 1][ch * 8]);
      }
#pragma unroll
      for (int i = 0; i < 4; i++) {
        int ch = i * 256 + tid;
        gl_lds16(Vh + (size_t)(it + 1) * 8192 + ch * 8, &Vb[cur ^ 1][ch * 8]);
      }
    }

    // QK for B (always) and A (while active), sharing the K-tile reads
    f32x4 sB[4], sA[4];
#pragma unroll
    for (int tj = 0; tj < 4; tj++) {
      sB[tj] = (f32x4){0.f, 0.f, 0.f, 0.f};
      sA[tj] = (f32x4){0.f, 0.f, 0.f, 0.f};
    }
#pragma unroll
    for (int ks = 0; ks < 4; ks++)
#pragma unroll
      for (int tj = 0; tj < 4; tj++) {
        bf16x8 bk = *(const bf16x8*)(&Kb[cur][(ks * 4 + tj) * 512 + lane * 8]);
        sB[tj] = __builtin_amdgcn_mfma_f32_16x16x32_bf16(aqB[ks], bk, sB[tj], 0, 0, 0);
        if (actA)
          sA[tj] = __builtin_amdgcn_mfma_f32_16x16x32_bf16(aqA[ks], bk, sA[tj], 0, 0, 0);
      }

    if (it == qb) {  // B diagonal tile: causal mask (last iteration)
#pragma unroll
      for (int tj = 0; tj < 4; tj++) {
        int kg = it * 64 + tj * 16 + c;
#pragma unroll
        for (int r = 0; r < 4; r++) {
          int qg = q0B + w * 16 + q * 4 + r;
          if (kg > qg) sB[tj][r] = -1e30f;
        }
      }
    }
    if (actA && it == qa) {  // A diagonal tile
#pragma unroll
      for (int tj = 0; tj < 4; tj++) {
        int kg = it * 64 + tj * 16 + c;
#pragma unroll
        for (int r = 0; r < 4; r++) {
          int qg = q0A + w * 16 + q * 4 + r;
          if (kg > qg) sA[tj][r] = -1e30f;
        }
      }
    }

    // online softmax for B (always) and A (while active)
#pragma unroll
    for (int r = 0; r < 4; r++) {
      float mx = fmaxf(fmaxf(sB[0][r], sB[1][r]), fmaxf(sB[2][r], sB[3][r]));
      mx = red_max16(mx);
      float mn = fmaxf(mB[r], mx);
      float alpha = __expf(mB[r] - mn);
      mB[r] = mn;
      float rs = 0.f;
#pragma unroll
      for (int tj = 0; tj < 4; tj++) {
        float e = __expf(sB[tj][r] - mn);
        sB[tj][r] = e;
        rs += e;
      }
      rs = red_sum16(rs);
      lB[r] = lB[r] * alpha + rs;
#pragma unroll
      for (int t = 0; t < 8; t++) oB[t][r] *= alpha;
    }
    if (actA) {
#pragma unroll
      for (int r = 0; r < 4; r++) {
        float mx = fmaxf(fmaxf(sA[0][r], sA[1][r]), fmaxf(sA[2][r], sA[3][r]));
        mx = red_max16(mx);
        float mn = fmaxf(mA[r], mx);
        float alpha = __expf(mA[r] - mn);
        mA[r] = mn;
        float rs = 0.f;
#pragma unroll
        for (int tj = 0; tj < 4; tj++) {
          float e = __expf(sA[tj][r] - mn);
          sA[tj][r] = e;
          rs += e;
        }
        rs = red_sum16(rs);
        lA[r] = lA[r] * alpha + rs;
#pragma unroll
        for (int t = 0; t < 8; t++) oA[t][r] *= alpha;
      }
    }

    // retire V(it): K(it+1)+V(it+1) (8 newer loads) may remain in flight
    if (it + 1 < n)
      asm volatile("s_waitcnt vmcnt(8)" ::: "memory");
    else
      asm volatile("s_waitcnt vmcnt(0)" ::: "memory");
    __builtin_amdgcn_s_barrier();  // B2: V(it) visible

    // P: C-layout -> wave-private A-layout regions (2 KB per wave each)
#pragma unroll
    for (int tj = 0; tj < 4; tj++) {
      int base = w * 1024 + (tj >> 1) * 512 + (((tj & 1) << 1) + (c >> 3)) * 128 + (c & 7);
#pragma unroll
      for (int r = 0; r < 4; r++) {
        PsB[base + (q * 4 + r) * 8] = (short)f2bf(sB[tj][r]);
        if (actA) PsA[base + (q * 4 + r) * 8] = (short)f2bf(sA[tj][r]);
      }
    }

#pragma unroll
    for (int ks2 = 0; ks2 < 2; ks2++) {
      bf16x8 ap = *(const bf16x8*)(PsB + w * 1024 + ks2 * 512 + lane * 8);
#pragma unroll
      for (int t = 0; t < 8; t++) {
        bf16x8 bv = *(const bf16x8*)(&Vb[cur][(ks2 * 8 + t) * 512 + lane * 8]);
        oB[t] = __builtin_amdgcn_mfma_f32_16x16x32_bf16(ap, bv, oB[t], 0, 0, 0);
      }
    }
    if (actA) {
#pragma unroll
      for (int ks2 = 0; ks2 < 2; ks2++) {
        bf16x8 ap = *(const bf16x8*)(PsA + w * 1024 + ks2 * 512 + lane * 8);
#pragma unroll
        for (int t = 0; t < 8; t++) {
          bf16x8 bv = *(const bf16x8*)(&Vb[cur][(ks2 * 8 + t) * 512 + lane * 8]);
          oA[t] = __builtin_amdgcn_mfma_f32_16x16x32_bf16(ap, bv, oA[t], 0, 0, 0);
        }
      }
    }
  }

  // epilogue: both tiles' outputs
#pragma unroll
  for (int r = 0; r < 4; r++) {
    float invA = 1.0f / lA[r];
    float invB = 1.0f / lB[r];
    int sgA = q0A + w * 16 + q * 4 + r;
    int sgB = q0B + w * 16 + q * 4 + r;
    float* dstA = out + (size_t)(b * S_ + sgA) * D_ + h * HD;
    float* dstB = out + (size_t)(b * S_ + sgB) * D_ + h * HD;
#pragma unroll
    for (int t = 0; t < 8; t++) {
      dstA[t * 16 + c] = oA[t][r] * invA;
      dstB[t * 16 + c] = oB[t][r] * invB;
    }
  }
}

extern "C" void kernel_launch(void* const* d_in, const int* in_sizes, int n_in,
                              void* d_out, int out_size, void* d_ws, size_t ws_size,
                              hipStream_t stream) {
  (void)in_sizes; (void)n_in; (void)out_size; (void)ws_size;
  const float* hs = (const float*)d_in[0];
  const float* wq = (const float*)d_in[1];
  const float* bq = (const float*)d_in[2];
  char* ws = (char*)d_ws;
  short* Xt = (short*)(ws);
  short* Wt = (short*)(ws + 16777216);
  short* Qg = (short*)(ws + 41943040);
  short* Kg = (short*)(ws + 58720256);
  short* Vg = (short*)(ws + 75497472);
  float2* tbl = (float2*)(ws + 92274688);

  hipLaunchKernelGGL(prep, dim3(5376), dim3(256), 0, stream, hs, Xt, wq, Wt, tbl);
  hipLaunchKernelGGL(qkv_gemm, dim3(48, 16), dim3(256), 0, stream, Xt, Wt, bq, tbl, Qg, Kg, Vg);
  hipLaunchKernelGGL(flash_attn, dim3(64, 8), dim3(256), 0, stream, Qg, Kg, Vg, (float*)d_out);
}